// Round 12
// baseline (53.521 us; speedup 1.0000x reference)
//
#include <hip/hip_runtime.h>
#include <math.h>

#define BB 256
#define FF 39
#define EE 16
#define II 741
#define BN_EPS 1e-5f
#define CPW 8            // channels per wave
#define NB 16            // batches per block (main kernel)
#define NCX 24           // channel-blocks: ceil(741/32)
#define NGY (BB / NB)    // 16
#define NROW (BB * FF)   // 9984
#define BFE (FF * EE)    // 624 floats per (batch, tensor)

typedef float vfloat4 __attribute__((ext_vector_type(4)));
typedef float vfloat2 __attribute__((ext_vector_type(2)));

// Compile-time strict-lower-triangle offsets: v[i] = (r*EE)<<16 | (c*EE),
// row-major pair order matching np.tril_indices(F, -1). Padded to 768 so
// tail waves can read per-lane without bounds checks.
struct OffTab { unsigned int v[768]; };
static constexpr OffTab make_off() {
    OffTab t{};
    int i = 0;
    for (int r = 1; r < FF; ++r)
        for (int c = 0; c < r; ++c) {
            t.v[i] = ((unsigned)(r * EE) << 16) | (unsigned)(c * EE);
            ++i;
        }
    for (; i < 768; ++i) t.v[i] = 0;
    return t;
}
__constant__ OffTab g_off = make_off();

// ws layout (float2 entries, TRANSPOSED f-major/b-minor):
//   Ti[f*BB + b] = (S, Q) of xi row (b,f)   at float2 [0 .. NROW)
//   Tj[f*BB + b] = (S, Q) of xj row (b,f)   at float2 [NROW .. 2*NROW)
// Transposed so the main kernel's preamble reads coalesced 64B segments.

__global__ void rowsumT_kernel(const float* __restrict__ xi,
                               const float* __restrict__ xj,
                               float* __restrict__ ws) {
    int t = blockIdx.x * blockDim.x + threadIdx.x;
    if (t >= 2 * NROW) return;
    int tensor = (t >= NROW) ? 1 : 0;
    int row = tensor ? (t - NROW) : t;
    int b = row / FF;
    int f = row - b * FF;
    const float* src = (tensor ? xj : xi) + row * EE;
    float s = 0.f, q = 0.f;
#pragma unroll
    for (int k = 0; k < 4; ++k) {
        vfloat4 v = reinterpret_cast<const vfloat4*>(src)[k];
        s += v.x + v.y + v.z + v.w;
        q += v.x * v.x + v.y * v.y + v.z * v.z + v.w * v.w;
    }
    vfloat2* base = reinterpret_cast<vfloat2*>(ws) + (tensor ? NROW : 0);
    vfloat2 e; e.x = s; e.y = q;
    base[f * BB + b] = e;
}

// out[b,i,e1,e2] = ((xj[b,r,e1]*xi[b,c,e2]) * a[i] + d[i]) * W[e1,e2]
// 4 waves/block; wave owns 8 consecutive channels x 16 batches.
// PREAMBLE (lane-group-parallel): 8 lanes per channel; each sub-lane
// reduces 32 batches from the transposed (S,Q) tables; 3 shfl_xor levels
// + 16 broadcasts. ~22 cross-lane ops total vs r10's 96.
__global__ __launch_bounds__(256) void
cross_bn_kernel(const float* __restrict__ xi,
                const float* __restrict__ xj,
                const float* __restrict__ W,
                const float* __restrict__ gamma,
                const float* __restrict__ beta,
                const float* __restrict__ ws,
                float* __restrict__ out) {
    const vfloat2* Ti = reinterpret_cast<const vfloat2*>(ws);
    const vfloat2* Tj = Ti + NROW;

    int t = threadIdx.x;
    int l = t & 63;        // lane in wave
    int e1 = l >> 2;       // 0..15
    int e2q = l & 3;       // float4 index along e2
    int wv = t >> 6;       // wave id 0..3

    int ibase = __builtin_amdgcn_readfirstlane(blockIdx.x * (4 * CPW) + wv * CPW);
    int b0 = blockIdx.y * NB;
    int nval = II - ibase;                  // valid channels this wave
    if (nval <= 0) return;                  // wv>=1 at cx==23 (no barriers used)
    if (nval > CPW) nval = CPW;

    vfloat4 w4 = reinterpret_cast<const vfloat4*>(W)[e1 * 4 + e2q];

    // ---------------- preamble: (a,d) for this wave's 8 channels ------------
    int g = l >> 3;        // channel group 0..7
    int s = l & 7;         // sub-lane within group
    {
        // intentionally nothing: scope clarity
    }
    unsigned og = g_off.v[ibase + g];       // per-lane const load (padded tab)
    int rb = (int)(og >> 16) * (BB / EE);   // r*256
    int cb = (int)(og & 0xffffu) * (BB / EE); // c*256

    float sS = 0.f, sQ = 0.f;
#pragma unroll
    for (int m = 0; m < 32; ++m) {
        int b = s + 8 * m;                  // group reads 8 consecutive b (64B)
        vfloat2 pj = Tj[rb + b];
        vfloat2 pi = Ti[cb + b];
        sS += pj.x * pi.x;
        sQ += pj.y * pi.y;
    }
#pragma unroll
    for (int off = 1; off < 8; off <<= 1) {
        sS += __shfl_xor(sS, off);
        sQ += __shfl_xor(sQ, off);
    }

    int joff[CPW], coff[CPW];
    float a[CPW], d[CPW];
    const float invN = 1.0f / (float)(BB * EE * EE);  // 1/65536
#pragma unroll
    for (int k = 0; k < CPW; ++k) {
        float sSk = __shfl(sS, k * 8);
        float sQk = __shfl(sQ, k * 8);
        unsigned ok = g_off.v[ibase + k];   // wave-uniform scalar load
        joff[k] = (int)(ok >> 16);
        coff[k] = (int)(ok & 0xffffu);
        int ii = ibase + k; if (ii > II - 1) ii = II - 1;  // clamp for tail
        float mean = sSk * invN;
        float var = sQk * invN - mean * mean;
        float inv_std = 1.0f / sqrtf(var + BN_EPS);
        a[k] = gamma[ii] * inv_std;
        d[k] = beta[ii] - mean * a[k];
    }

    // ---------------- streaming store phase ----------------
    if (nval == CPW) {
#pragma unroll 2
        for (int bb = 0; bb < NB; ++bb) {
            int b = b0 + bb;
            const float* xib = xi + b * BFE;
            const float* xjb = xj + b * BFE;
            float* outb = out + (size_t)b * (II * EE * EE)
                          + (size_t)ibase * (EE * EE);
#pragma unroll
            for (int k = 0; k < CPW; ++k) {
                float xjs = xjb[joff[k] + e1];
                vfloat4 xi4 = reinterpret_cast<const vfloat4*>(xib + coff[k])[e2q];
                vfloat4 o4;
                o4.x = (xjs * xi4.x * a[k] + d[k]) * w4.x;
                o4.y = (xjs * xi4.y * a[k] + d[k]) * w4.y;
                o4.z = (xjs * xi4.z * a[k] + d[k]) * w4.z;
                o4.w = (xjs * xi4.w * a[k] + d[k]) * w4.w;
                reinterpret_cast<vfloat4*>(outb + k * (EE * EE))[l] = o4;
            }
        }
    } else {
        // tail (cx==23, wv==0: channels 736..740)
        for (int bb = 0; bb < NB; ++bb) {
            int b = b0 + bb;
            const float* xib = xi + b * BFE;
            const float* xjb = xj + b * BFE;
            float* outb = out + (size_t)b * (II * EE * EE);
            for (int k = 0; k < nval; ++k) {
                int i = ibase + k;
                float xjs = xjb[joff[k] + e1];
                vfloat4 xi4 = reinterpret_cast<const vfloat4*>(xib + coff[k])[e2q];
                vfloat4 o4;
                o4.x = (xjs * xi4.x * a[k] + d[k]) * w4.x;
                o4.y = (xjs * xi4.y * a[k] + d[k]) * w4.y;
                o4.z = (xjs * xi4.z * a[k] + d[k]) * w4.z;
                o4.w = (xjs * xi4.w * a[k] + d[k]) * w4.w;
                reinterpret_cast<vfloat4*>(outb + (size_t)i * (EE * EE))[l] = o4;
            }
        }
    }
}

extern "C" void kernel_launch(void* const* d_in, const int* in_sizes, int n_in,
                              void* d_out, int out_size, void* d_ws, size_t ws_size,
                              hipStream_t stream) {
    const float* xi = (const float*)d_in[0];
    const float* xj = (const float*)d_in[1];
    const float* W = (const float*)d_in[2];
    const float* gamma = (const float*)d_in[3];
    const float* beta = (const float*)d_in[4];
    float* out = (float*)d_out;
    float* ws = (float*)d_ws;

    rowsumT_kernel<<<dim3((2 * NROW + 255) / 256), 256, 0, stream>>>(xi, xj, ws);
    cross_bn_kernel<<<dim3(NCX, NGY), 256, 0, stream>>>(xi, xj, W, gamma, beta, ws, out);
}

// Round 13
// 44.650 us; speedup vs baseline: 1.1987x; 1.1987x over previous
//
#include <hip/hip_runtime.h>
#include <math.h>

#define BB 256
#define FF 39
#define EE 16
#define II 741
#define BN_EPS 1e-5f
#define BFE (FF * EE)    // 624 floats per (batch, tensor)
#define NROW (BB * FF)
#define MAINBLK 2048     // main kernel grid; 8192 waves

typedef float vfloat4 __attribute__((ext_vector_type(4)));
typedef float vfloat2 __attribute__((ext_vector_type(2)));

// Compile-time strict-lower-triangle offsets: v[i] = (r*EE)<<16 | (c*EE),
// row-major pair order matching np.tril_indices(F, -1).
struct OffTab { unsigned int v[II]; };
static constexpr OffTab make_off() {
    OffTab t{};
    int i = 0;
    for (int r = 1; r < FF; ++r)
        for (int c = 0; c < r; ++c) {
            t.v[i] = ((unsigned)(r * EE) << 16) | (unsigned)(c * EE);
            ++i;
        }
    return t;
}
__constant__ OffTab g_off = make_off();

// ws layout (floats): T2[I] = (a, d) per channel. ~6 KB.

// One wave per channel (r6-proven, ~2-3 us). Lanes split the batch dim
// (4 fully-unrolled independent load rounds); butterfly-reduce; lane 0
// folds BN stats into affine (a,d).
__global__ __launch_bounds__(256) void
stats_kernel(const float* __restrict__ xi,
             const float* __restrict__ xj,
             const float* __restrict__ gamma,
             const float* __restrict__ beta,
             float* __restrict__ ws) {
    int wid = (blockIdx.x * blockDim.x + threadIdx.x) >> 6;  // global wave = channel
    int lane = threadIdx.x & 63;
    if (wid >= II) return;
    int i = wid;
    unsigned o = g_off.v[i];
    int joff = (int)(o >> 16);
    int coff = (int)(o & 0xffffu);

    float sumS = 0.f, sumQ = 0.f;
#pragma unroll
    for (int b = lane; b < BB; b += 64) {
        const vfloat4* xjr = reinterpret_cast<const vfloat4*>(xj + b * BFE + joff);
        const vfloat4* xic = reinterpret_cast<const vfloat4*>(xi + b * BFE + coff);
        float sj = 0.f, qj = 0.f, si = 0.f, qi = 0.f;
#pragma unroll
        for (int k = 0; k < 4; ++k) {
            vfloat4 vj = xjr[k];
            vfloat4 vi = xic[k];
            sj += vj.x + vj.y + vj.z + vj.w;
            qj += vj.x * vj.x + vj.y * vj.y + vj.z * vj.z + vj.w * vj.w;
            si += vi.x + vi.y + vi.z + vi.w;
            qi += vi.x * vi.x + vi.y * vi.y + vi.z * vi.z + vi.w * vi.w;
        }
        sumS += sj * si;
        sumQ += qj * qi;
    }
#pragma unroll
    for (int off = 32; off > 0; off >>= 1) {
        sumS += __shfl_xor(sumS, off);
        sumQ += __shfl_xor(sumQ, off);
    }
    if (lane == 0) {
        const float invN = 1.0f / (float)(BB * EE * EE);  // 1/65536
        float mean = sumS * invN;
        float ex2 = sumQ * invN;
        float var = ex2 - mean * mean;
        float inv_std = 1.0f / sqrtf(var + BN_EPS);
        float a = gamma[i] * inv_std;
        float d = beta[i] - mean * a;
        vfloat2 e;
        e.x = a; e.y = d;
        reinterpret_cast<vfloat2*>(ws)[i] = e;
    }
}

// Fill-shaped streaming kernel: one wave = one linear 1KB chunk n = (b,i);
// grid-stride over the 741*256 = 189696 chunks. Consecutive waves write
// consecutive 1KB chunks -> the HBM write stream is a pure linear sweep,
// exactly like the 6.7 TB/s fill kernel. All reads are wave-uniform scalar
// (off/a/d) or L2-hot vector (xj scalar-per-lane, xi 16B).
__global__ __launch_bounds__(256) void
cross_bn_linear(const float* __restrict__ xi,
                const float* __restrict__ xj,
                const float* __restrict__ W,
                const float* __restrict__ ws,
                float* __restrict__ out) {
    const vfloat2* T2 = reinterpret_cast<const vfloat2*>(ws);

    int t = threadIdx.x;
    int l = t & 63;        // lane in wave
    int e1 = l >> 2;       // 0..15
    int e2q = l & 3;       // float4 index along e2

    vfloat4 w4 = reinterpret_cast<const vfloat4*>(W)[e1 * 4 + e2q];

    const int NWAVES = MAINBLK * 4;
    const int TOT = II * BB;  // 189696 chunks of 256 floats
    int wave = (blockIdx.x * 256 + t) >> 6;  // wave-uniform

#pragma unroll 2
    for (int n = wave; n < TOT; n += NWAVES) {
        int b = n / II;            // wave-uniform scalar magic-div
        int i = n - b * II;
        unsigned o = g_off.v[i];   // wave-uniform scalar load
        int joff = (int)(o >> 16);
        int coff = (int)(o & 0xffffu);
        vfloat2 ad = T2[i];        // wave-uniform scalar load (8B)
        float xjs = xj[b * BFE + joff + e1];
        vfloat4 xi4 = reinterpret_cast<const vfloat4*>(xi + b * BFE + coff)[e2q];
        vfloat4 o4;
        o4.x = (xjs * xi4.x * ad.x + ad.y) * w4.x;
        o4.y = (xjs * xi4.y * ad.x + ad.y) * w4.y;
        o4.z = (xjs * xi4.z * ad.x + ad.y) * w4.z;
        o4.w = (xjs * xi4.w * ad.x + ad.y) * w4.w;
        reinterpret_cast<vfloat4*>(out + (size_t)n * 256)[l] = o4;
    }
}

extern "C" void kernel_launch(void* const* d_in, const int* in_sizes, int n_in,
                              void* d_out, int out_size, void* d_ws, size_t ws_size,
                              hipStream_t stream) {
    const float* xi = (const float*)d_in[0];
    const float* xj = (const float*)d_in[1];
    const float* W = (const float*)d_in[2];
    const float* gamma = (const float*)d_in[3];
    const float* beta = (const float*)d_in[4];
    float* out = (float*)d_out;
    float* ws = (float*)d_ws;

    stats_kernel<<<dim3((II * 64 + 255) / 256), 256, 0, stream>>>(xi, xj, gamma, beta, ws);
    cross_bn_linear<<<dim3(MAINBLK), 256, 0, stream>>>(xi, xj, W, ws, out);
}